// Round 1
// baseline (5205.921 us; speedup 1.0000x reference)
//
#include <hip/hip_runtime.h>
#include <hip/hip_bf16.h>
#include <cstddef>

// Problem constants
#define B 4
#define T 2048
#define C 1024
#define NQ 8
#define D 128
#define M_ROWS (B * T)   // 8192

// GEMM tiling
#define BM 64
#define BN 64
#define BK 16

// -------------------- Tiled fp32 GEMM body --------------------
// A: [M, K] row-major; W: [K, N] row-major; Cout: [M, N] row-major.
// 256 threads, each computes a 4x4 output patch of a 64x64 tile.
template <int N, int K, bool HAS_BIAS>
__device__ __forceinline__ void gemm_body(const float* __restrict__ A,
                                          const float* __restrict__ W,
                                          float* __restrict__ Cout,
                                          const float* __restrict__ bias,
                                          int bx, int by) {
    __shared__ float As[BK][BM];
    __shared__ float Ws[BK][BN];

    const int tid = threadIdx.x;        // 0..255
    const int tx  = tid & 15;           // 0..15 -> 4 cols each
    const int ty  = tid >> 4;           // 0..15 -> 4 rows each
    const int row0 = by * BM;
    const int col0 = bx * BN;

    // A staging: 64 rows x 16 k, one float4 along K per thread
    const int am = tid >> 2;            // 0..63
    const int ak = (tid & 3) << 2;      // 0,4,8,12
    // W staging: 16 k x 64 n, one float4 along N per thread
    const int wk = tid >> 4;            // 0..15
    const int wn = (tid & 15) << 2;     // 0..60

    float acc[4][4] = {};

    for (int k0 = 0; k0 < K; k0 += BK) {
        const float4 av = *(const float4*)(A + (size_t)(row0 + am) * K + (k0 + ak));
        const float4 wv = *(const float4*)(W + (size_t)(k0 + wk) * N + (col0 + wn));
        As[ak + 0][am] = av.x;
        As[ak + 1][am] = av.y;
        As[ak + 2][am] = av.z;
        As[ak + 3][am] = av.w;
        *(float4*)(&Ws[wk][wn]) = wv;
        __syncthreads();

#pragma unroll
        for (int kk = 0; kk < BK; ++kk) {
            const float4 a = *(const float4*)(&As[kk][ty << 2]);
            const float4 b = *(const float4*)(&Ws[kk][tx << 2]);
            acc[0][0] += a.x * b.x; acc[0][1] += a.x * b.y; acc[0][2] += a.x * b.z; acc[0][3] += a.x * b.w;
            acc[1][0] += a.y * b.x; acc[1][1] += a.y * b.y; acc[1][2] += a.y * b.z; acc[1][3] += a.y * b.w;
            acc[2][0] += a.z * b.x; acc[2][1] += a.z * b.y; acc[2][2] += a.z * b.z; acc[2][3] += a.z * b.w;
            acc[3][0] += a.w * b.x; acc[3][1] += a.w * b.y; acc[3][2] += a.w * b.z; acc[3][3] += a.w * b.w;
        }
        __syncthreads();
    }

#pragma unroll
    for (int i = 0; i < 4; ++i) {
        const int row = row0 + (ty << 2) + i;
        float4 o;
        o.x = acc[i][0]; o.y = acc[i][1]; o.z = acc[i][2]; o.w = acc[i][3];
        if (HAS_BIAS) {
            const int col = col0 + (tx << 2);
            o.x += bias[col + 0];
            o.y += bias[col + 1];
            o.z += bias[col + 2];
            o.w += bias[col + 3];
        }
        *(float4*)(Cout + (size_t)row * N + col0 + (tx << 2)) = o;
    }
}

// -------------------- QKV fused GEMM --------------------
// grid.z: 0 -> k = x@Wk, 1 -> v = x@Wv, 2..9 -> q[h] = x@Wq[h]
__global__ __launch_bounds__(256) void gemm_qkv(const float* __restrict__ x,
                                                const float* __restrict__ Wk,
                                                const float* __restrict__ Wv,
                                                const float* __restrict__ Wq,
                                                float* __restrict__ kb,
                                                float* __restrict__ vb,
                                                float* __restrict__ qb) {
    const int z = blockIdx.z;
    const float* W;
    float* out;
    if (z == 0)      { W = Wk; out = kb; }
    else if (z == 1) { W = Wv; out = vb; }
    else {
        W   = Wq + (size_t)(z - 2) * C * D;
        out = qb + (size_t)(z - 2) * M_ROWS * D;
    }
    gemm_body<D, C, false>(x, W, out, nullptr, blockIdx.x, blockIdx.y);
}

// -------------------- Projection GEMM (+bias) --------------------
__global__ __launch_bounds__(256) void gemm_proj(const float* __restrict__ att,
                                                 const float* __restrict__ Wp,
                                                 const float* __restrict__ bp,
                                                 float* __restrict__ out) {
    gemm_body<C, NQ * D, true>(att, Wp, out, bp, blockIdx.x, blockIdx.y);
}

// -------------------- Attention (online softmax, one wave per query) ------
// q: [NQ, B*T, D]  k,v: [B*T, D]  att out: [B, T, NQ, D]
__global__ __launch_bounds__(256) void attn(const float* __restrict__ q,
                                            const float* __restrict__ k,
                                            const float* __restrict__ v,
                                            float* __restrict__ att) {
    const int lane = threadIdx.x & 63;
    const int wave = threadIdx.x >> 6;               // 0..3
    const int t    = blockIdx.x * 4 + wave;          // query index in [0, T)
    const int h    = blockIdx.y;
    const int b    = blockIdx.z;
    const float scale = 0.03125f;                    // 1024^-0.5

    const float2 qv = *(const float2*)(q + ((size_t)h * B * T + (size_t)b * T + t) * D + (lane << 1));
    const float* kb = k + (size_t)b * T * D;
    const float* vb = v + (size_t)b * T * D;

    float m = -INFINITY;
    float l = 0.0f;
    float2 acc = {0.0f, 0.0f};

    for (int s = 0; s <= t; ++s) {
        const float2 kv = *(const float2*)(kb + (size_t)s * D + (lane << 1));
        float dot = qv.x * kv.x + qv.y * kv.y;
#pragma unroll
        for (int off = 32; off > 0; off >>= 1) dot += __shfl_xor(dot, off);
        dot *= scale;

        const float mnew  = fmaxf(m, dot);
        const float alpha = __expf(m - mnew);        // first iter: exp(-inf)=0
        const float p     = __expf(dot - mnew);
        l = l * alpha + p;

        const float2 vv = *(const float2*)(vb + (size_t)s * D + (lane << 1));
        acc.x = acc.x * alpha + p * vv.x;
        acc.y = acc.y * alpha + p * vv.y;
        m = mnew;
    }

    const float inv = 1.0f / l;
    float2 o;
    o.x = acc.x * inv;
    o.y = acc.y * inv;
    *(float2*)(att + (((size_t)b * T + t) * NQ + h) * D + (lane << 1)) = o;
}

// -------------------- Launch --------------------
extern "C" void kernel_launch(void* const* d_in, const int* in_sizes, int n_in,
                              void* d_out, int out_size, void* d_ws, size_t ws_size,
                              hipStream_t stream) {
    const float* x  = (const float*)d_in[0];
    const float* Wk = (const float*)d_in[1];
    const float* Wv = (const float*)d_in[2];
    const float* Wq = (const float*)d_in[3];
    const float* Wp = (const float*)d_in[4];
    const float* bp = (const float*)d_in[5];
    float* out = (float*)d_out;

    float* ws  = (float*)d_ws;
    float* kb  = ws;                                 // [B*T, D]      1M floats
    float* vb  = kb + (size_t)B * T * D;             // [B*T, D]      1M floats
    float* qb  = vb + (size_t)B * T * D;             // [NQ, B*T, D]  8M floats
    float* att = qb + (size_t)NQ * B * T * D;        // [B, T, NQ, D] 8M floats

    // 1) k, v, q
    dim3 g1(D / BN, M_ROWS / BM, 2 + NQ);            // (2, 128, 10)
    gemm_qkv<<<g1, 256, 0, stream>>>(x, Wk, Wv, Wq, kb, vb, qb);

    // 2) causal attention with online softmax
    dim3 g2(T / 4, NQ, B);                           // (512, 8, 4)
    attn<<<g2, 256, 0, stream>>>(qb, kb, vb, att);

    // 3) output projection
    dim3 g3(C / BN, M_ROWS / BM, 1);                 // (16, 128)
    gemm_proj<<<g3, 256, 0, stream>>>(att, Wp, bp, out);
}

// Round 2
// 881.265 us; speedup vs baseline: 5.9073x; 5.9073x over previous
//
#include <hip/hip_runtime.h>
#include <hip/hip_bf16.h>
#include <cstddef>
#include <cstdint>

// Problem constants
#define B 4
#define T 2048
#define C 1024
#define NQ 8
#define D 128
#define M_ROWS (B * T)   // 8192

// GEMM tiling
#define BM 64
#define BN 64
#define BK 16

typedef __bf16 bf16x8 __attribute__((ext_vector_type(8)));
typedef float  f32x4  __attribute__((ext_vector_type(4)));

__device__ __forceinline__ ushort f2bf(float f) {
    union { float f; uint32_t u; } v; v.f = f;
    const uint32_t r = (v.u + 0x7fffu + ((v.u >> 16) & 1u)) >> 16;
    return (ushort)r;
}

// -------------------- Tiled fp32 GEMM body --------------------
// A: [M, K] row-major f32; W: [K, N] row-major f32; Cout row-major.
// 256 threads, each computes a 4x4 output patch of a 64x64 tile.
template <int N, int K, bool HAS_BIAS, bool BF16_OUT>
__device__ __forceinline__ void gemm_body(const float* __restrict__ A,
                                          const float* __restrict__ W,
                                          void* __restrict__ Cout_,
                                          const float* __restrict__ bias,
                                          int bx, int by) {
    __shared__ float As[BK][BM];
    __shared__ float Ws[BK][BN];

    const int tid = threadIdx.x;        // 0..255
    const int tx  = tid & 15;           // 4 cols each
    const int ty  = tid >> 4;           // 4 rows each
    const int row0 = by * BM;
    const int col0 = bx * BN;

    const int am = tid >> 2;            // 0..63
    const int ak = (tid & 3) << 2;      // 0,4,8,12
    const int wk = tid >> 4;            // 0..15
    const int wn = (tid & 15) << 2;     // 0..60

    float acc[4][4] = {};

    for (int k0 = 0; k0 < K; k0 += BK) {
        const float4 av = *(const float4*)(A + (size_t)(row0 + am) * K + (k0 + ak));
        const float4 wv = *(const float4*)(W + (size_t)(k0 + wk) * N + (col0 + wn));
        As[ak + 0][am] = av.x;
        As[ak + 1][am] = av.y;
        As[ak + 2][am] = av.z;
        As[ak + 3][am] = av.w;
        *(float4*)(&Ws[wk][wn]) = wv;
        __syncthreads();

#pragma unroll
        for (int kk = 0; kk < BK; ++kk) {
            const float4 a = *(const float4*)(&As[kk][ty << 2]);
            const float4 b = *(const float4*)(&Ws[kk][tx << 2]);
            acc[0][0] += a.x * b.x; acc[0][1] += a.x * b.y; acc[0][2] += a.x * b.z; acc[0][3] += a.x * b.w;
            acc[1][0] += a.y * b.x; acc[1][1] += a.y * b.y; acc[1][2] += a.y * b.z; acc[1][3] += a.y * b.w;
            acc[2][0] += a.z * b.x; acc[2][1] += a.z * b.y; acc[2][2] += a.z * b.z; acc[2][3] += a.z * b.w;
            acc[3][0] += a.w * b.x; acc[3][1] += a.w * b.y; acc[3][2] += a.w * b.z; acc[3][3] += a.w * b.w;
        }
        __syncthreads();
    }

#pragma unroll
    for (int i = 0; i < 4; ++i) {
        const int row = row0 + (ty << 2) + i;
        const int col = col0 + (tx << 2);
        float o0 = acc[i][0], o1 = acc[i][1], o2 = acc[i][2], o3 = acc[i][3];
        if (HAS_BIAS) {
            o0 += bias[col + 0]; o1 += bias[col + 1];
            o2 += bias[col + 2]; o3 += bias[col + 3];
        }
        if (BF16_OUT) {
            ushort4 o;
            o.x = f2bf(o0); o.y = f2bf(o1); o.z = f2bf(o2); o.w = f2bf(o3);
            *(ushort4*)((ushort*)Cout_ + (size_t)row * N + col) = o;
        } else {
            float4 o; o.x = o0; o.y = o1; o.z = o2; o.w = o3;
            *(float4*)((float*)Cout_ + (size_t)row * N + col) = o;
        }
    }
}

// -------------------- QKV fused GEMM (bf16 outputs) --------------------
// grid.z: 0 -> k = x@Wk, 1 -> v = x@Wv, 2..9 -> q[h] = x@Wq[h]
__global__ __launch_bounds__(256) void gemm_qkv(const float* __restrict__ x,
                                                const float* __restrict__ Wk,
                                                const float* __restrict__ Wv,
                                                const float* __restrict__ Wq,
                                                ushort* __restrict__ kb,
                                                ushort* __restrict__ vb,
                                                ushort* __restrict__ qb) {
    const int z = blockIdx.z;
    const float* W;
    ushort* out;
    if (z == 0)      { W = Wk; out = kb; }
    else if (z == 1) { W = Wv; out = vb; }
    else {
        W   = Wq + (size_t)(z - 2) * C * D;
        out = qb + (size_t)(z - 2) * M_ROWS * D;
    }
    gemm_body<D, C, false, true>(x, W, out, nullptr, blockIdx.x, blockIdx.y);
}

// -------------------- Projection GEMM (+bias, f32) --------------------
__global__ __launch_bounds__(256) void gemm_proj(const float* __restrict__ att,
                                                 const float* __restrict__ Wp,
                                                 const float* __restrict__ bp,
                                                 float* __restrict__ out) {
    gemm_body<C, NQ * D, true, false>(att, Wp, out, bp, blockIdx.x, blockIdx.y);
}

// -------------------- MFMA flash attention --------------------
// q: [NQ, B*T, D] bf16;  k,v: [B*T, D] bf16;  att out: [B, T, NQ, D] f32
// Block: 256 threads = 4 waves; each wave owns 16 queries; block owns 64
// consecutive queries of one (b,h). Key loop in tiles of 32.
__global__ __launch_bounds__(256) void attn_mfma(const ushort* __restrict__ q,
                                                 const ushort* __restrict__ k,
                                                 const ushort* __restrict__ v,
                                                 float* __restrict__ att) {
    __shared__ ushort Ks[32][136];    // keys x d, +8 pad -> 2-way banks only
    __shared__ ushort Vt[128][40];    // d x keys (transposed), pad 32->40
    __shared__ ushort Pt[4][16][32];  // per-wave P tile (C-layout -> A-layout)

    const int tid  = threadIdx.x;
    const int lane = tid & 63;
    const int w    = tid >> 6;        // wave 0..3
    const int col  = lane & 15;
    const int quad = lane >> 4;
    const int qb_i = blockIdx.x;
    const int h    = blockIdx.y;
    const int b    = blockIdx.z;
    const int q0   = qb_i * 64;
    const int myq  = q0 + w * 16 + col;   // A-frag row m = lane&15

    // Q fragments, held in registers for the whole kernel (16 VGPRs)
    const ushort* qrow = q + ((size_t)h * M_ROWS + (size_t)b * T + myq) * D;
    bf16x8 qf[4];
#pragma unroll
    for (int kb2 = 0; kb2 < 4; ++kb2)
        qf[kb2] = *reinterpret_cast<const bf16x8*>(qrow + kb2 * 32 + quad * 8);

    const ushort* kbase = k + (size_t)b * T * D;
    const ushort* vbase = v + (size_t)b * T * D;

    f32x4 O[8];
#pragma unroll
    for (int i = 0; i < 8; ++i) O[i] = (f32x4){0.f, 0.f, 0.f, 0.f};
    float m_r[4] = {-1e30f, -1e30f, -1e30f, -1e30f};
    float l_r[4] = {0.f, 0.f, 0.f, 0.f};

    const int ntiles = (q0 + 64) / 32;    // = 2*qb_i + 2
    const int sk_key = tid >> 3;          // 0..31 staging row
    const int sk_c   = tid & 7;           // staging chunk

    for (int it = 0; it < ntiles; ++it) {
        const int s0 = it * 32;
        __syncthreads();
        // stage K tile (row-major) and V tile (transposed), bf16
        {
            const ushort* gk = kbase + (size_t)(s0 + sk_key) * D;
            const ushort* gv = vbase + (size_t)(s0 + sk_key) * D;
#pragma unroll
            for (int cc = 0; cc < 2; ++cc) {
                const int c = sk_c + cc * 8;
                *reinterpret_cast<uint4*>(&Ks[sk_key][c * 8]) =
                    *reinterpret_cast<const uint4*>(gk + c * 8);
            }
#pragma unroll
            for (int cc = 0; cc < 2; ++cc) {
                const int c = sk_c + cc * 8;
                ushort tmp[8];
                *reinterpret_cast<uint4*>(tmp) = *reinterpret_cast<const uint4*>(gv + c * 8);
#pragma unroll
                for (int i = 0; i < 8; ++i) Vt[c * 8 + i][sk_key] = tmp[i];
            }
        }
        __syncthreads();

        // S = Q K^T  (two 16-key subtiles, 4 MFMAs over D each)
        f32x4 S[2];
#pragma unroll
        for (int sub = 0; sub < 2; ++sub) {
            f32x4 acc = (f32x4){0.f, 0.f, 0.f, 0.f};
#pragma unroll
            for (int kb2 = 0; kb2 < 4; ++kb2) {
                bf16x8 kf = *reinterpret_cast<const bf16x8*>(
                    &Ks[sub * 16 + col][kb2 * 32 + quad * 8]);
                acc = __builtin_amdgcn_mfma_f32_16x16x32_bf16(qf[kb2], kf, acc, 0, 0, 0);
            }
            S[sub] = acc;
        }

        // scale + causal mask (C-layout: row = quad*4+r, col = key)
        float sv[2][4];
#pragma unroll
        for (int sub = 0; sub < 2; ++sub) {
            const int key = s0 + sub * 16 + col;
#pragma unroll
            for (int r = 0; r < 4; ++r) {
                const int qq = q0 + w * 16 + quad * 4 + r;
                const float s = S[sub][r] * 0.03125f;   // C^-0.5
                sv[sub][r] = (key > qq) ? -1e30f : s;
            }
        }

        // online softmax: row reductions across the 16-lane col group
        float mx[4];
#pragma unroll
        for (int r = 0; r < 4; ++r) {
            float t0 = fmaxf(sv[0][r], sv[1][r]);
#pragma unroll
            for (int off = 1; off < 16; off <<= 1) t0 = fmaxf(t0, __shfl_xor(t0, off));
            mx[r] = t0;
        }
        float alpha[4];
#pragma unroll
        for (int r = 0; r < 4; ++r) {
            const float mnew = fmaxf(m_r[r], mx[r]);
            alpha[r] = __expf(m_r[r] - mnew);
            const float p0 = __expf(sv[0][r] - mnew);
            const float p1 = __expf(sv[1][r] - mnew);
            m_r[r] = mnew;
            float s = p0 + p1;
#pragma unroll
            for (int off = 1; off < 16; off <<= 1) s += __shfl_xor(s, off);
            l_r[r] = l_r[r] * alpha[r] + s;
            Pt[w][quad * 4 + r][col]      = f2bf(p0);
            Pt[w][quad * 4 + r][col + 16] = f2bf(p1);
        }

        // rescale O
#pragma unroll
        for (int nt = 0; nt < 8; ++nt) {
#pragma unroll
            for (int r = 0; r < 4; ++r) O[nt][r] *= alpha[r];
        }

        // P: C-layout -> A-layout via per-wave LDS round-trip
        bf16x8 pa = *reinterpret_cast<const bf16x8*>(&Pt[w][col][quad * 8]);

        // O += P V   (8 d-tiles of 16, K=32 keys per MFMA)
#pragma unroll
        for (int nt = 0; nt < 8; ++nt) {
            bf16x8 vf = *reinterpret_cast<const bf16x8*>(&Vt[nt * 16 + col][quad * 8]);
            O[nt] = __builtin_amdgcn_mfma_f32_16x16x32_bf16(pa, vf, O[nt], 0, 0, 0);
        }
    }

    // epilogue: O / l  -> att[b][t][h][d]
#pragma unroll
    for (int r = 0; r < 4; ++r) {
        const float inv = 1.0f / l_r[r];
        const int t = q0 + w * 16 + quad * 4 + r;
        float* orow = att + (((size_t)b * T + t) * NQ + h) * D;
#pragma unroll
        for (int nt = 0; nt < 8; ++nt) orow[nt * 16 + col] = O[nt][r] * inv;
    }
}

// -------------------- Launch --------------------
extern "C" void kernel_launch(void* const* d_in, const int* in_sizes, int n_in,
                              void* d_out, int out_size, void* d_ws, size_t ws_size,
                              hipStream_t stream) {
    const float* x  = (const float*)d_in[0];
    const float* Wk = (const float*)d_in[1];
    const float* Wv = (const float*)d_in[2];
    const float* Wq = (const float*)d_in[3];
    const float* Wp = (const float*)d_in[4];
    const float* bp = (const float*)d_in[5];
    float* out = (float*)d_out;

    char* ws = (char*)d_ws;
    ushort* kb  = (ushort*)ws;                                   // 2 MB
    ushort* vb  = (ushort*)(ws + (size_t)2 * 1024 * 1024);       // 2 MB
    ushort* qb  = (ushort*)(ws + (size_t)4 * 1024 * 1024);       // 16 MB
    float*  att = (float*) (ws + (size_t)20 * 1024 * 1024);      // 32 MB

    // 1) k, v, q (bf16 out)
    dim3 g1(D / BN, M_ROWS / BM, 2 + NQ);            // (2, 128, 10)
    gemm_qkv<<<g1, 256, 0, stream>>>(x, Wk, Wv, Wq, kb, vb, qb);

    // 2) MFMA flash attention
    dim3 g2(T / 64, NQ, B);                          // (32, 8, 4)
    attn_mfma<<<g2, 256, 0, stream>>>(qb, kb, vb, att);

    // 3) output projection
    dim3 g3(C / BN, M_ROWS / BM, 1);                 // (16, 128)
    gemm_proj<<<g3, 256, 0, stream>>>(att, Wp, bp, out);
}

// Round 3
// 386.817 us; speedup vs baseline: 13.4584x; 2.2783x over previous
//
#include <hip/hip_runtime.h>
#include <hip/hip_bf16.h>
#include <cstddef>
#include <cstdint>

// Problem constants
#define B 4
#define T 2048
#define C 1024
#define NQ 8
#define D 128
#define M_ROWS (B * T)          // 8192
#define NTOT (2 * D + NQ * D)   // 1280: [k | v | q0..q7]

typedef __bf16 bf16x8 __attribute__((ext_vector_type(8)));
typedef float  f32x4  __attribute__((ext_vector_type(4)));

__device__ __forceinline__ ushort f2bf(float f) {
    union { float f; uint32_t u; } v; v.f = f;
    const uint32_t r = (v.u + 0x7fffu + ((v.u >> 16) & 1u)) >> 16;
    return (ushort)r;
}

__device__ __forceinline__ void gld_lds16(const ushort* g, ushort* lds_uniform) {
    __builtin_amdgcn_global_load_lds(
        (const __attribute__((address_space(1))) void*)g,
        (__attribute__((address_space(3))) void*)lds_uniform, 16, 0, 0);
}

// -------------------- x f32 -> bf16 --------------------
__global__ __launch_bounds__(256) void xcvt(const float* __restrict__ x,
                                            ushort* __restrict__ xb) {
    const size_t i = ((size_t)blockIdx.x * 256 + threadIdx.x) * 8;
    const float4 a = *(const float4*)(x + i);
    const float4 b = *(const float4*)(x + i + 4);
    uint4 o;
    o.x = f2bf(a.x) | ((uint32_t)f2bf(a.y) << 16);
    o.y = f2bf(a.z) | ((uint32_t)f2bf(a.w) << 16);
    o.z = f2bf(b.x) | ((uint32_t)f2bf(b.y) << 16);
    o.w = f2bf(b.z) | ((uint32_t)f2bf(b.w) << 16);
    *(uint4*)(xb + i) = o;
}

// -------------------- weight transpose+convert: src f32 [1024][NC] -> dst bf16 [NC][1024]
__device__ __forceinline__ void wtrans_body(const float* __restrict__ src,
                                            ushort* __restrict__ dst, int NC,
                                            int bx, int by) {
    __shared__ ushort Ts[64][72];
    const int tid = threadIdx.x;
    const int k0 = by * 64, c0 = bx * 64;
    {
        const int r = tid >> 2, cq = tid & 3;
#pragma unroll
        for (int i = 0; i < 4; ++i) {
            const int cc = cq * 16 + i * 4;
            const float4 v = *(const float4*)(src + (size_t)(k0 + r) * NC + c0 + cc);
            uint2 o;
            o.x = f2bf(v.x) | ((uint32_t)f2bf(v.y) << 16);
            o.y = f2bf(v.z) | ((uint32_t)f2bf(v.w) << 16);
            *(uint2*)(&Ts[r][cc]) = o;
        }
    }
    __syncthreads();
    {
        const int n = tid >> 2, kq = tid & 3;
        ushort vv[16];
#pragma unroll
        for (int j = 0; j < 16; ++j) vv[j] = Ts[kq * 16 + j][n];
        uint4 o0, o1;
        o0.x = vv[0] | ((uint32_t)vv[1] << 16);  o0.y = vv[2] | ((uint32_t)vv[3] << 16);
        o0.z = vv[4] | ((uint32_t)vv[5] << 16);  o0.w = vv[6] | ((uint32_t)vv[7] << 16);
        o1.x = vv[8] | ((uint32_t)vv[9] << 16);  o1.y = vv[10] | ((uint32_t)vv[11] << 16);
        o1.z = vv[12] | ((uint32_t)vv[13] << 16); o1.w = vv[14] | ((uint32_t)vv[15] << 16);
        ushort* d = dst + (size_t)(c0 + n) * C + k0 + kq * 16;
        *(uint4*)d = o0;
        *(uint4*)(d + 8) = o1;
    }
}

// z: 0 -> Wk (rows 0..127), 1 -> Wv (128..255), 2..9 -> Wq[h] (256+128h..)
__global__ __launch_bounds__(256) void wtrans_qkv(const float* __restrict__ Wk,
                                                  const float* __restrict__ Wv,
                                                  const float* __restrict__ Wq,
                                                  ushort* __restrict__ WcatT) {
    const int z = blockIdx.z;
    const float* src;
    int rbase;
    if (z == 0)      { src = Wk; rbase = 0; }
    else if (z == 1) { src = Wv; rbase = D; }
    else             { src = Wq + (size_t)(z - 2) * C * D; rbase = 2 * D + (z - 2) * D; }
    wtrans_body(src, WcatT + (size_t)rbase * C, D, blockIdx.x, blockIdx.y);
}

__global__ __launch_bounds__(256) void wtrans_p(const float* __restrict__ Wp,
                                                ushort* __restrict__ WpT) {
    wtrans_body(Wp, WpT, C, blockIdx.x, blockIdx.y);
}

// -------------------- v transpose with per-32-key interleave permutation -----
// vb rows are qkv[row][D..2D); out vbT[d][g*32 + pi(k)], pi(k) = (k&15)*2 + (k>>4)
__global__ __launch_bounds__(256) void vtrans(const ushort* __restrict__ qkv,
                                              ushort* __restrict__ vbT) {
    __shared__ ushort Ts[64][136];
    const int tid = threadIdx.x;
    const int kb0 = blockIdx.x * 64;
    {
        const int r = tid >> 2, cq = tid & 3;
        const ushort* src = qkv + (size_t)(kb0 + r) * NTOT + D;
#pragma unroll
        for (int i = 0; i < 4; ++i) {
            const int cc = (cq * 4 + i) * 8;
            *(uint4*)(&Ts[r][cc]) = *(const uint4*)(src + cc);
        }
    }
    __syncthreads();
    {
        const int d = tid >> 1, half = tid & 1;
        ushort vv[32];
#pragma unroll
        for (int k = 0; k < 32; ++k) vv[k] = Ts[half * 32 + k][d];
        uint32_t dw[16];
#pragma unroll
        for (int i = 0; i < 16; ++i) dw[i] = vv[i] | ((uint32_t)vv[16 + i] << 16);
        uint32_t* dst = (uint32_t*)(vbT + (size_t)d * M_ROWS + kb0 + half * 32);
#pragma unroll
        for (int i = 0; i < 4; ++i)
            *(uint4*)(dst + i * 4) = *(uint4*)(&dw[i * 4]);
    }
}

// -------------------- MFMA GEMM: A bf16 [M][1024] @ Bt bf16 [N][1024]^T -----
// 128x128 tile, BK=32, 4 waves each computing 64x64 (4x4 16x16x32 MFMAs).
template <bool BF16_OUT>
__global__ __launch_bounds__(256) void gemm_mfma(const ushort* __restrict__ A,
                                                 const ushort* __restrict__ Bt,
                                                 void* __restrict__ Cout,
                                                 const float* __restrict__ bias,
                                                 const int Nout) {
    __shared__ ushort As[128 * 32];
    __shared__ ushort Bs[128 * 32];
    const int tid  = threadIdx.x;
    const int lane = tid & 63;
    const int w    = tid >> 6;
    const int col  = lane & 15;
    const int quad = lane >> 4;
    const int row0 = blockIdx.y * 128;
    const int col0 = blockIdx.x * 128;
    const int wm = w & 1, wn = w >> 1;

    const int srow = lane >> 2;         // staging row within 16-row chunk
    const int skk  = (lane & 3) * 8;    // staging k offset (ushorts)

    f32x4 acc[4][4];
#pragma unroll
    for (int i = 0; i < 4; ++i)
#pragma unroll
        for (int j = 0; j < 4; ++j) acc[i][j] = (f32x4){0.f, 0.f, 0.f, 0.f};

    for (int k0 = 0; k0 < C; k0 += 32) {
        __syncthreads();
#pragma unroll
        for (int j = 0; j < 2; ++j) {
            const int ci = w * 2 + j;              // LDS chunk 0..7 (1KB each)
            const int r  = ci * 16 + srow;         // tile row 0..127
            gld_lds16(A  + (size_t)(row0 + r) * C + k0 + skk, &As[ci * 512]);
            gld_lds16(Bt + (size_t)(col0 + r) * C + k0 + skk, &Bs[ci * 512]);
        }
        __syncthreads();

        bf16x8 af[4], bfr[4];
#pragma unroll
        for (int i = 0; i < 4; ++i)
            af[i] = *(const bf16x8*)&As[(wm * 64 + i * 16 + col) * 32 + quad * 8];
#pragma unroll
        for (int j = 0; j < 4; ++j)
            bfr[j] = *(const bf16x8*)&Bs[(wn * 64 + j * 16 + col) * 32 + quad * 8];
#pragma unroll
        for (int i = 0; i < 4; ++i)
#pragma unroll
            for (int j = 0; j < 4; ++j)
                acc[i][j] = __builtin_amdgcn_mfma_f32_16x16x32_bf16(af[i], bfr[j], acc[i][j], 0, 0, 0);
    }

#pragma unroll
    for (int i = 0; i < 4; ++i) {
#pragma unroll
        for (int r = 0; r < 4; ++r) {
            const int grow = row0 + wm * 64 + i * 16 + quad * 4 + r;
#pragma unroll
            for (int j = 0; j < 4; ++j) {
                const int gcol = col0 + wn * 64 + j * 16 + col;
                const float v = acc[i][j][r];
                if (BF16_OUT) {
                    ((ushort*)Cout)[(size_t)grow * Nout + gcol] = f2bf(v);
                } else {
                    ((float*)Cout)[(size_t)grow * Nout + gcol] = v + bias[gcol];
                }
            }
        }
    }
}

// -------------------- MFMA flash attention --------------------
// qkv: [M_ROWS][NTOT] bf16 (k|v|q), vbT: [D][M_ROWS] bf16 (key-permuted),
// attb out: [M_ROWS][C] bf16 (row = b*T+t, col = h*D+d)
__global__ __launch_bounds__(256) void attn_mfma(const ushort* __restrict__ qkv,
                                                 const ushort* __restrict__ vbT,
                                                 ushort* __restrict__ attb) {
    __shared__ ushort Ks[32][136];   // keys x d (natural key order)
    __shared__ ushort Vt[128][40];   // d x keys (permuted order)
    __shared__ ushort Pt[4][16][40]; // per-wave P (q-rows x permuted keys)

    const int tid  = threadIdx.x;
    const int lane = tid & 63;
    const int w    = tid >> 6;
    const int col  = lane & 15;
    const int quad = lane >> 4;
    const int qb_i = (gridDim.x - 1) - blockIdx.x;   // longest blocks first
    const int h    = blockIdx.y;
    const int b    = blockIdx.z;
    const int q0   = qb_i * 64;
    const int myq  = q0 + w * 16 + col;

    const ushort* qrow = qkv + (size_t)(b * T + myq) * NTOT + 2 * D + h * D;
    bf16x8 qf[4];
#pragma unroll
    for (int kb2 = 0; kb2 < 4; ++kb2)
        qf[kb2] = *(const bf16x8*)(qrow + kb2 * 32 + quad * 8);

    const ushort* kbase = qkv + (size_t)b * T * NTOT;   // k at col 0

    f32x4 O[8];
#pragma unroll
    for (int i = 0; i < 8; ++i) O[i] = (f32x4){0.f, 0.f, 0.f, 0.f};
    float m_r[4] = {-1e30f, -1e30f, -1e30f, -1e30f};
    float l_r[4] = {0.f, 0.f, 0.f, 0.f};

    const int ntiles = (q0 + 64) / 32;
    const int sk_key = tid >> 3;          // 0..31
    const int sk_c   = tid & 7;
    const int vd     = tid >> 1;          // 0..127
    const int vhalf  = tid & 1;

    for (int it = 0; it < ntiles; ++it) {
        const int s0 = it * 32;
        __syncthreads();
        // K tile: row-major, natural order
        {
            const ushort* gk = kbase + (size_t)(s0 + sk_key) * NTOT;
#pragma unroll
            for (int cc = 0; cc < 2; ++cc) {
                const int c = (sk_c + cc * 8) * 8;
                *(uint4*)(&Ks[sk_key][c]) = *(const uint4*)(gk + c);
            }
        }
        // V tile: from pre-transposed+permuted vbT, contiguous copies
        {
            const ushort* gv = vbT + (size_t)vd * M_ROWS + b * T + s0 + vhalf * 16;
#pragma unroll
            for (int i = 0; i < 2; ++i)
                *(uint4*)(&Vt[vd][vhalf * 16 + i * 8]) = *(const uint4*)(gv + i * 8);
        }
        __syncthreads();

        // S = Q K^T
        f32x4 S[2];
#pragma unroll
        for (int sub = 0; sub < 2; ++sub) {
            f32x4 a = (f32x4){0.f, 0.f, 0.f, 0.f};
#pragma unroll
            for (int kb2 = 0; kb2 < 4; ++kb2) {
                bf16x8 kf = *(const bf16x8*)(&Ks[sub * 16 + col][kb2 * 32 + quad * 8]);
                a = __builtin_amdgcn_mfma_f32_16x16x32_bf16(qf[kb2], kf, a, 0, 0, 0);
            }
            S[sub] = a;
        }

        // scale + causal mask (C-layout: row = quad*4+r, col = key)
        float sv[2][4];
#pragma unroll
        for (int sub = 0; sub < 2; ++sub) {
            const int key = s0 + sub * 16 + col;
#pragma unroll
            for (int r = 0; r < 4; ++r) {
                const int qq = q0 + w * 16 + quad * 4 + r;
                const float s = S[sub][r] * 0.03125f;
                sv[sub][r] = (key > qq) ? -1e30f : s;
            }
        }

        float alpha[4];
#pragma unroll
        for (int r = 0; r < 4; ++r) {
            float t0 = fmaxf(sv[0][r], sv[1][r]);
#pragma unroll
            for (int off = 1; off < 16; off <<= 1) t0 = fmaxf(t0, __shfl_xor(t0, off));
            const float mnew = fmaxf(m_r[r], t0);
            alpha[r] = __expf(m_r[r] - mnew);
            const float p0 = __expf(sv[0][r] - mnew);
            const float p1 = __expf(sv[1][r] - mnew);
            m_r[r] = mnew;
            float s = p0 + p1;
#pragma unroll
            for (int off = 1; off < 16; off <<= 1) s += __shfl_xor(s, off);
            l_r[r] = l_r[r] * alpha[r] + s;
            // packed dword write: keys col (low) and col+16 (high) == permuted pos 2col,2col+1
            *(uint32_t*)(&Pt[w][quad * 4 + r][col * 2]) =
                f2bf(p0) | ((uint32_t)f2bf(p1) << 16);
        }

#pragma unroll
        for (int nt = 0; nt < 8; ++nt)
#pragma unroll
            for (int r = 0; r < 4; ++r) O[nt][r] *= alpha[r];

        // P (A-layout, permuted k) and V (B-layout, same permutation)
        bf16x8 pa = *(const bf16x8*)(&Pt[w][col][quad * 8]);
#pragma unroll
        for (int nt = 0; nt < 8; ++nt) {
            bf16x8 vf = *(const bf16x8*)(&Vt[nt * 16 + col][quad * 8]);
            O[nt] = __builtin_amdgcn_mfma_f32_16x16x32_bf16(pa, vf, O[nt], 0, 0, 0);
        }
    }

    // epilogue -> attb[b*T+t][h*D + d], bf16
#pragma unroll
    for (int r = 0; r < 4; ++r) {
        const float inv = 1.0f / l_r[r];
        const int t = q0 + w * 16 + quad * 4 + r;
        ushort* orow = attb + (size_t)(b * T + t) * C + h * D;
#pragma unroll
        for (int nt = 0; nt < 8; ++nt) orow[nt * 16 + col] = f2bf(O[nt][r] * inv);
    }
}

// -------------------- Launch --------------------
extern "C" void kernel_launch(void* const* d_in, const int* in_sizes, int n_in,
                              void* d_out, int out_size, void* d_ws, size_t ws_size,
                              hipStream_t stream) {
    const float* x  = (const float*)d_in[0];
    const float* Wk = (const float*)d_in[1];
    const float* Wv = (const float*)d_in[2];
    const float* Wq = (const float*)d_in[3];
    const float* Wp = (const float*)d_in[4];
    const float* bp = (const float*)d_in[5];
    float* out = (float*)d_out;

    char* ws = (char*)d_ws;
    ushort* xb    = (ushort*)ws;                                  // 16 MB (aliased by attb later)
    ushort* attb  = xb;
    ushort* qkv   = (ushort*)(ws + (size_t)16  * 1024 * 1024);    // 20 MB
    ushort* WcatT = (ushort*)(ws + (size_t)36  * 1024 * 1024);    // 2.5 MB
    ushort* WpT   = (ushort*)(ws + (size_t)39  * 1024 * 1024);    // 2 MB
    ushort* vbT   = (ushort*)(ws + (size_t)41  * 1024 * 1024);    // 2 MB

    // 1) conversions
    xcvt<<<(size_t)M_ROWS * C / (256 * 8), 256, 0, stream>>>(x, xb);
    wtrans_qkv<<<dim3(D / 64, C / 64, 2 + NQ), 256, 0, stream>>>(Wk, Wv, Wq, WcatT);
    wtrans_p<<<dim3(C / 64, C / 64), 256, 0, stream>>>(Wp, WpT);

    // 2) fused QKV GEMM: [8192,1024] @ [1024,1280] -> qkv bf16
    gemm_mfma<true><<<dim3(NTOT / 128, M_ROWS / 128), 256, 0, stream>>>(
        xb, WcatT, qkv, nullptr, NTOT);

    // 3) v transpose (with key permutation)
    vtrans<<<M_ROWS / 64, 256, 0, stream>>>(qkv, vbT);

    // 4) flash attention
    attn_mfma<<<dim3(T / 64, NQ, B), 256, 0, stream>>>(qkv, vbT, attb);

    // 5) projection: [8192,1024] @ [1024,1024] + bp -> out f32
    gemm_mfma<false><<<dim3(C / 128, M_ROWS / 128), 256, 0, stream>>>(
        attb, WpT, out, bp, C);
}